// Round 4
// baseline (802.091 us; speedup 1.0000x reference)
//
#include <hip/hip_runtime.h>
#include <cstddef>

// Problem constants (from reference)
#define BB   16
#define HHY  128
#define WWX  256
#define CC   64
#define DDp  12
#define HOUT 1024
#define WOUT 2048

// ---------------------------------------------------------------------------
// Kernel 1: cost volume. cost[b,h,w,d] = sum_c |L[b,h,w,c] - R[b,h,w-d,c]|
// (zero-pad shift: w<d contributes sum_c |L|).
// Block = one (b,h) row, thread = w. 16-channel chunks (64 B/w per pass =
// exactly one cache line -> no half-line HBM waste), staged via registers:
// next chunk's global loads are issued right after the barrier and complete
// under the current chunk's compute (software pipeline at 4 blocks/CU).
// LDS stride 20 floats: 20w mod 32 covers all bank quads -> b128-friendly.
// ---------------------------------------------------------------------------
#define CCH 16
#define LST 20

__global__ __launch_bounds__(256) void cost_volume_k(const float* __restrict__ L,
                                                     const float* __restrict__ R,
                                                     float* __restrict__ cost) {
  __shared__ float lsL[WWX * LST];   // 20 KB
  __shared__ float lsR[WWX * LST];   // 20 KB
  const int t = threadIdx.x;
  const int h = blockIdx.x;
  const int b = blockIdx.y;
  const size_t rowbase = ((size_t)(b * HHY + h)) * WWX;
  const float* Lrow = L + rowbase * CC;
  const float* Rrow = R + rowbase * CC;

  float acc[DDp];
#pragma unroll
  for (int d = 0; d < DDp; ++d) acc[d] = 0.f;

  float4 pL[4], pR[4];
  // prologue: chunk 0
#pragma unroll
  for (int j = 0; j < 4; ++j) {
    const int i = t + 256 * j;       // float4 id in [0,1024)
    const int w = i >> 2;
    const int r4 = (i & 3) << 2;
    pL[j] = *(const float4*)(Lrow + (size_t)w * CC + r4);
    pR[j] = *(const float4*)(Rrow + (size_t)w * CC + r4);
  }

#pragma unroll
  for (int c0 = 0; c0 < CC; c0 += CCH) {
    // stage regs -> LDS (previous readers done: trailing barrier below)
#pragma unroll
    for (int j = 0; j < 4; ++j) {
      const int i = t + 256 * j;
      const int w = i >> 2;
      const int r4 = (i & 3) << 2;
      *(float4*)(&lsL[w * LST + r4]) = pL[j];
      *(float4*)(&lsR[w * LST + r4]) = pR[j];
    }
    __syncthreads();

    // prefetch next chunk (in flight during compute)
    if (c0 + CCH < CC) {
#pragma unroll
      for (int j = 0; j < 4; ++j) {
        const int i = t + 256 * j;
        const int w = i >> 2;
        const int r4 = (i & 3) << 2;
        pL[j] = *(const float4*)(Lrow + (size_t)w * CC + c0 + CCH + r4);
        pR[j] = *(const float4*)(Rrow + (size_t)w * CC + c0 + CCH + r4);
      }
    }

    float l[CCH];
#pragma unroll
    for (int k = 0; k < CCH / 4; ++k)
      ((float4*)l)[k] = *(const float4*)(&lsL[t * LST + 4 * k]);

    float sl = 0.f;
#pragma unroll
    for (int k = 0; k < CCH; ++k) sl += fabsf(l[k]);

#pragma unroll
    for (int d = 0; d < DDp; ++d) {
      if (t >= d) {
        const float* rp = &lsR[(t - d) * LST];
        float a = 0.f;
#pragma unroll
        for (int k = 0; k < CCH / 4; ++k) {
          const float4 r4 = *(const float4*)(rp + 4 * k);
          a += fabsf(l[4 * k + 0] - r4.x) + fabsf(l[4 * k + 1] - r4.y) +
               fabsf(l[4 * k + 2] - r4.z) + fabsf(l[4 * k + 3] - r4.w);
        }
        acc[d] += a;
      } else {
        acc[d] += sl;
      }
    }
    __syncthreads();  // readers done before next iteration's stores
  }

  float* cp = cost + (rowbase + t) * DDp;
#pragma unroll
  for (int d = 0; d < DDp; d += 4)
    *(float4*)(cp + d) = make_float4(acc[d], acc[d + 1], acc[d + 2], acc[d + 3]);
}

// ---------------------------------------------------------------------------
// Conv3d 3x3x3 over (H,W,D), SAME zero pad, layout [B,H,W,D,CIN].
// Round-2 row structure (block = one (b,h) row, thread = w) + two changes:
//  1. kh-row staging is software-pipelined through registers (issue next row's
//     global loads right after the barrier, compute under them).
//  2. Input-stationary inner loop: one float4 of x live at a time (vo loop)
//     scattering into the (d = vo+1-kd) accumulators -> low VGPR pressure so
//     the prefetch registers don't cost occupancy.
// Weights stay as per-tap global loads (wave-uniform -> scalar path).
// FUSE_SM: COUT=1 final conv + softmax(-cost) + disparity regression.
// ---------------------------------------------------------------------------
template <int CIN, int COUT, bool RELU, bool FUSE_SM>
__global__ __launch_bounds__(256) void conv3d_k(const float* __restrict__ x,
                                                const float* __restrict__ wt,
                                                const float* __restrict__ bs,
                                                float* __restrict__ y) {
  constexpr int DC = DDp * CIN;               // 12 or 48
  constexpr int S  = DC + (CIN == 1 ? 8 : 4); // 20 or 52 (bank spread)
  constexpr int NPF = (WWX * DC / 4) / 256;   // 3 or 12 float4 per thread
  __shared__ float ls[WWX * S];

  const int t = threadIdx.x;
  const int w = t;
  const int h = blockIdx.x;
  const int b = blockIdx.y;

  float acc[DDp][COUT];
#pragma unroll
  for (int co = 0; co < COUT; ++co) {
    const float bv = bs[co];
#pragma unroll
    for (int d = 0; d < DDp; ++d) acc[d][co] = bv;
  }

  const int kh_lo = (h == 0) ? 1 : 0;
  const int kh_hi = (h == HHY - 1) ? 1 : 2;

  float4 pre[NPF];
  {
    const float* xr = x + ((size_t)(b * HHY + (h + kh_lo - 1)) * WWX) * DC;
#pragma unroll
    for (int j = 0; j < NPF; ++j) pre[j] = ((const float4*)xr)[t + 256 * j];
  }

#pragma unroll
  for (int kh = 0; kh < 3; ++kh) {
    if (kh < kh_lo || kh > kh_hi) continue;  // block-uniform

    // store prefetched row -> LDS (padded stride)
#pragma unroll
    for (int j = 0; j < NPF; ++j) {
      const int fi4 = t + 256 * j;
      const int ws_ = fi4 / (DC / 4);
      const int r = (fi4 - ws_ * (DC / 4)) * 4;
      *(float4*)(&ls[ws_ * S + r]) = pre[j];
    }
    __syncthreads();

    // prefetch next valid row
    if (kh < kh_hi) {
      const float* xr = x + ((size_t)(b * HHY + (h + kh)) * WWX) * DC;
#pragma unroll
      for (int j = 0; j < NPF; ++j) pre[j] = ((const float4*)xr)[t + 256 * j];
    }

#pragma unroll
    for (int kw = 0; kw < 3; ++kw) {
      const int ww = w + kw - 1;
      if (ww < 0 || ww >= WWX) continue;  // divergent only at row edges
      const float* lp = &ls[ww * S];

      const float* wp = wt + (size_t)(kh * 3 + kw) * 3 * CIN * COUT;
      float wr[3 * CIN * COUT];
#pragma unroll
      for (int i = 0; i < 3 * CIN * COUT; ++i) wr[i] = wp[i];

      if (CIN == 1) {
        float v[DDp];
#pragma unroll
        for (int k = 0; k < DDp / 4; ++k)
          ((float4*)v)[k] = *(const float4*)(lp + 4 * k);
#pragma unroll
        for (int vo = 0; vo < DDp; ++vo)
#pragma unroll
          for (int kd = 0; kd < 3; ++kd) {
            const int d = vo + 1 - kd;
            if (d < 0 || d >= DDp) continue;
#pragma unroll
            for (int co = 0; co < COUT; ++co)
              acc[d][co] += v[vo] * wr[kd * COUT + co];
          }
      } else {
#pragma unroll
        for (int vo = 0; vo < DDp; ++vo) {
          const float4 x4 = *(const float4*)(lp + vo * CIN);
          const float xv[4] = {x4.x, x4.y, x4.z, x4.w};
#pragma unroll
          for (int kd = 0; kd < 3; ++kd) {
            const int d = vo + 1 - kd;
            if (d < 0 || d >= DDp) continue;
#pragma unroll
            for (int ci = 0; ci < CIN; ++ci)
#pragma unroll
              for (int co = 0; co < COUT; ++co)
                acc[d][co] += xv[ci] * wr[(kd * CIN + ci) * COUT + co];
          }
        }
      }
    }
    __syncthreads();  // readers done before next row's stores
  }

  if (FUSE_SM) {
    float mn = acc[0][0];
#pragma unroll
    for (int d = 1; d < DDp; ++d) mn = fminf(mn, acc[d][0]);
    float s = 0.f, sw = 0.f;
#pragma unroll
    for (int d = 0; d < DDp; ++d) {
      const float e = __expf(mn - acc[d][0]);
      s += e;
      sw += e * (float)d;
    }
    y[(size_t)(b * HHY + h) * WWX + w] = sw / s;
  } else {
    float ov[DDp * COUT];
#pragma unroll
    for (int d = 0; d < DDp; ++d)
#pragma unroll
      for (int co = 0; co < COUT; ++co) {
        float r = acc[d][co];
        if (RELU) r = fmaxf(r, 0.f);
        ov[d * COUT + co] = r;
      }
    float* yp = y + ((size_t)(b * HHY + h) * WWX + w) * (DDp * COUT);
#pragma unroll
    for (int i = 0; i < (DDp * COUT) / 4; ++i)
      ((float4*)yp)[i] = ((float4*)ov)[i];
  }
}

// ---------------------------------------------------------------------------
// 8x bilinear upsample, 4 outputs per thread. A 4-aligned output group maps to
// exactly 2 input columns and 2 rows -> 4 loads, 1 float4 store. jax
// half-pixel convention; edge renormalization == index clamp.
// ---------------------------------------------------------------------------
__global__ __launch_bounds__(256) void resize4_k(const float* __restrict__ pred,
                                                 float* __restrict__ out) {
  const int idx = blockIdx.x * 256 + threadIdx.x;   // group id
  const int xg = idx & 511;
  const int y = (idx >> 9) & 1023;
  const int b = idx >> 19;

  const int parity = xg & 1;
  const int m = xg >> 1;
  const int x0 = m - 1 + parity;
  const int x0c = max(x0, 0);
  const int x1c = min(x0 + 1, WWX - 1);
  const float wx0 = (parity ? 0.0625f : 0.5625f);

  const int py = y & 7;
  const int my = y >> 3;
  const int y0 = my - 1 + (py >= 4 ? 1 : 0);
  const float wy = (py >= 4) ? 0.0625f + (py - 4) * 0.125f : 0.5625f + py * 0.125f;
  const int y0c = max(y0, 0);
  const int y1c = min(y0 + 1, HHY - 1);

  const float* pb = pred + (size_t)b * HHY * WWX;
  const float a = pb[y0c * WWX + x0c];
  const float bv = pb[y0c * WWX + x1c];
  const float c = pb[y1c * WWX + x0c];
  const float d = pb[y1c * WWX + x1c];

  const float top0 = a + (bv - a) * wx0;
  const float bot0 = c + (d - c) * wx0;
  const float dtop = (bv - a) * 0.125f;
  const float dbot = (d - c) * 0.125f;

  float4 o;
  o.x = top0 + wy * (bot0 - top0);
  o.y = (top0 + dtop) + wy * ((bot0 + dbot) - (top0 + dtop));
  o.z = (top0 + 2.f * dtop) + wy * ((bot0 + 2.f * dbot) - (top0 + 2.f * dtop));
  o.w = (top0 + 3.f * dtop) + wy * ((bot0 + 3.f * dbot) - (top0 + 3.f * dtop));

  *(float4*)(out + (size_t)idx * 4) = o;
}

// ---------------------------------------------------------------------------
extern "C" void kernel_launch(void* const* d_in, const int* in_sizes, int n_in,
                              void* d_out, int out_size, void* d_ws, size_t ws_size,
                              hipStream_t stream) {
  const float* feat_l = (const float*)d_in[0];
  const float* feat_r = (const float*)d_in[1];
  const float* w0 = (const float*)d_in[2];
  const float* b0 = (const float*)d_in[3];
  const float* w1 = (const float*)d_in[4];
  const float* b1 = (const float*)d_in[5];
  const float* w2 = (const float*)d_in[6];
  const float* b2 = (const float*)d_in[7];
  const float* w3 = (const float*)d_in[8];
  const float* b3 = (const float*)d_in[9];
  const float* wf = (const float*)d_in[10];
  const float* bf = (const float*)d_in[11];
  float* out = (float*)d_out;

  // ws: two ping-pong buffers of [B,H,W,D,4] f32 (100.7 MB each). cost volume
  // ([B,H,W,D], 25 MB) at start of bufA; pred ([B,H,W], 2 MB) at start of
  // bufB after the final fused conv.
  char* ws = (char*)d_ws;
  const size_t buf_bytes = (size_t)BB * HHY * WWX * DDp * 4 * sizeof(float);
  float* bufA = (float*)ws;
  float* bufB = (float*)(ws + buf_bytes);

  dim3 blk(256);
  dim3 grid_row(HHY, BB);

  cost_volume_k<<<grid_row, blk, 0, stream>>>(feat_l, feat_r, bufA);
  conv3d_k<1, 4, true, false><<<grid_row, blk, 0, stream>>>(bufA, w0, b0, bufB);
  conv3d_k<4, 4, true, false><<<grid_row, blk, 0, stream>>>(bufB, w1, b1, bufA);
  conv3d_k<4, 4, true, false><<<grid_row, blk, 0, stream>>>(bufA, w2, b2, bufB);
  conv3d_k<4, 4, true, false><<<grid_row, blk, 0, stream>>>(bufB, w3, b3, bufA);
  conv3d_k<4, 1, false, true><<<grid_row, blk, 0, stream>>>(bufA, wf, bf, bufB);

  const int ngroups = BB * HOUT * (WOUT / 4);
  resize4_k<<<dim3(ngroups / 256), blk, 0, stream>>>(bufB, out);
}

// Round 5
// 411.954 us; speedup vs baseline: 1.9470x; 1.9470x over previous
//
#include <hip/hip_runtime.h>
#include <cstddef>

// Problem constants (from reference)
#define BB   16
#define HHY  128
#define WWX  256
#define CC   64
#define DDp  12
#define HOUT 1024
#define WOUT 2048

// ---------------------------------------------------------------------------
// Kernel 1: cost volume. cost[b,h,w,d] = sum_c |L[b,h,w,c] - R[b,h,w-d,c]|
// (zero-pad shift: w<d contributes sum_c |L|).
// Block = one (b,h) row, thread = w. Only R is staged in LDS (L[w,:] is
// consumed exclusively by thread w -> loaded straight to registers as
// per-thread 64B line-aligned chunks). 16-channel chunks; LDS 20 KB ->
// 8 blocks/CU occupancy ceiling.
// ---------------------------------------------------------------------------
#define CCH 16
#define LST 20

__global__ __launch_bounds__(256) void cost_volume_k(const float* __restrict__ L,
                                                     const float* __restrict__ R,
                                                     float* __restrict__ cost) {
  __shared__ float lsR[WWX * LST];   // 20 KB
  const int t = threadIdx.x;
  const int h = blockIdx.x;
  const int b = blockIdx.y;
  const size_t rowbase = ((size_t)(b * HHY + h)) * WWX;
  const float* Lrow = L + rowbase * CC;
  const float* Rrow = R + rowbase * CC;

  float acc[DDp];
#pragma unroll
  for (int d = 0; d < DDp; ++d) acc[d] = 0.f;

  for (int c0 = 0; c0 < CC; c0 += CCH) {
    __syncthreads();  // previous chunk's readers done
#pragma unroll
    for (int j = 0; j < 4; ++j) {
      const int i = t + 256 * j;     // float4 id in [0,1024)
      const int w = i >> 2;
      const int r4 = (i & 3) << 2;
      *(float4*)(&lsR[w * LST + r4]) =
          *(const float4*)(Rrow + (size_t)w * CC + c0 + r4);
    }
    __syncthreads();

    // L chunk direct from global: thread t reads its own 64B (line-aligned).
    float l[CCH];
#pragma unroll
    for (int k = 0; k < CCH / 4; ++k)
      ((float4*)l)[k] = *(const float4*)(Lrow + (size_t)t * CC + c0 + 4 * k);

    float sl = 0.f;
#pragma unroll
    for (int k = 0; k < CCH; ++k) sl += fabsf(l[k]);

#pragma unroll
    for (int d = 0; d < DDp; ++d) {
      if (t >= d) {
        const float* rp = &lsR[(t - d) * LST];
        float a = 0.f;
#pragma unroll
        for (int k = 0; k < CCH / 4; ++k) {
          const float4 r4 = *(const float4*)(rp + 4 * k);
          a += fabsf(l[4 * k + 0] - r4.x) + fabsf(l[4 * k + 1] - r4.y) +
               fabsf(l[4 * k + 2] - r4.z) + fabsf(l[4 * k + 3] - r4.w);
        }
        acc[d] += a;
      } else {
        acc[d] += sl;
      }
    }
  }

  float* cp = cost + (rowbase + t) * DDp;
#pragma unroll
  for (int d = 0; d < DDp; d += 4)
    *(float4*)(cp + d) = make_float4(acc[d], acc[d + 1], acc[d + 2], acc[d + 3]);
}

// ---------------------------------------------------------------------------
// Conv3d 3x3x3 over (H,W,D), SAME zero pad, layout [B,H,W,D,CIN].
// Round-2 structure: block = one (b,h) row, thread = w, kh rows staged one at
// a time in LDS with coalesced loads (padded stride). No register prefetch
// (round-4 spilled). Inner loop is input-stationary per float4 (vo loop) to
// keep VGPRs low. Weights are wave-uniform global loads -> scalar path.
// 1D grid with XCD-contiguous h-chunk remap: XCD k owns h in [16k, 16k+16)
// for each b, so the 3 blocks consuming each input row share one XCD's L2.
// FUSE_SM: COUT=1 final conv + softmax(-cost) + disparity regression.
// ---------------------------------------------------------------------------
template <int CIN, int COUT, bool RELU, bool FUSE_SM>
__global__ __launch_bounds__(256) void conv3d_k(const float* __restrict__ x,
                                                const float* __restrict__ wt,
                                                const float* __restrict__ bs,
                                                float* __restrict__ y) {
  constexpr int DC = DDp * CIN;               // 12 or 48
  constexpr int S  = DC + (CIN == 1 ? 8 : 4); // 20 or 52 (bank spread)
  __shared__ float ls[WWX * S];

  const int w = threadIdx.x;
  const int id = blockIdx.x;                       // 0..2047
  const int h = ((id & 7) << 4) | ((id >> 3) & 15);  // XCD-contiguous h chunks
  const int b = id >> 7;

  float acc[DDp][COUT];
#pragma unroll
  for (int co = 0; co < COUT; ++co) {
    const float bv = bs[co];
#pragma unroll
    for (int d = 0; d < DDp; ++d) acc[d][co] = bv;
  }

#pragma unroll
  for (int kh = 0; kh < 3; ++kh) {
    const int hh = h + kh - 1;
    if (hh < 0 || hh >= HHY) continue;  // block-uniform

    __syncthreads();  // previous row's readers done
    const float* xr = x + ((size_t)(b * HHY + hh) * WWX) * DC;
    constexpr int N4 = WWX * DC / 4;    // 768 or 3072
#pragma unroll
    for (int j = 0; j < N4 / 256; ++j) {
      const int f = (w + 256 * j) * 4;
      const int ww = f / DC;
      const int r = f - ww * DC;
      *(float4*)(&ls[ww * S + r]) = *(const float4*)(xr + f);
    }
    __syncthreads();

#pragma unroll
    for (int kw = 0; kw < 3; ++kw) {
      const int ww = w + kw - 1;
      if (ww < 0 || ww >= WWX) continue;  // divergent only at row edges
      const float* lp = &ls[ww * S];

      const float* wp = wt + (size_t)(kh * 3 + kw) * 3 * CIN * COUT;
      float wr[3 * CIN * COUT];
#pragma unroll
      for (int i = 0; i < 3 * CIN * COUT; ++i) wr[i] = wp[i];

      if (CIN == 1) {
        float v[DDp];
#pragma unroll
        for (int k = 0; k < DDp / 4; ++k)
          ((float4*)v)[k] = *(const float4*)(lp + 4 * k);
#pragma unroll
        for (int vo = 0; vo < DDp; ++vo)
#pragma unroll
          for (int kd = 0; kd < 3; ++kd) {
            const int d = vo + 1 - kd;
            if (d < 0 || d >= DDp) continue;
#pragma unroll
            for (int co = 0; co < COUT; ++co)
              acc[d][co] += v[vo] * wr[kd * COUT + co];
          }
      } else {
#pragma unroll
        for (int vo = 0; vo < DDp; ++vo) {
          const float4 x4 = *(const float4*)(lp + vo * CIN);
          const float xv[4] = {x4.x, x4.y, x4.z, x4.w};
#pragma unroll
          for (int kd = 0; kd < 3; ++kd) {
            const int d = vo + 1 - kd;
            if (d < 0 || d >= DDp) continue;
#pragma unroll
            for (int ci = 0; ci < CIN; ++ci)
#pragma unroll
              for (int co = 0; co < COUT; ++co)
                acc[d][co] += xv[ci] * wr[(kd * CIN + ci) * COUT + co];
          }
        }
      }
    }
  }

  if (FUSE_SM) {
    float mn = acc[0][0];
#pragma unroll
    for (int d = 1; d < DDp; ++d) mn = fminf(mn, acc[d][0]);
    float s = 0.f, sw = 0.f;
#pragma unroll
    for (int d = 0; d < DDp; ++d) {
      const float e = __expf(mn - acc[d][0]);
      s += e;
      sw += e * (float)d;
    }
    y[(size_t)(b * HHY + h) * WWX + w] = sw / s;
  } else {
    float ov[DDp * COUT];
#pragma unroll
    for (int d = 0; d < DDp; ++d)
#pragma unroll
      for (int co = 0; co < COUT; ++co) {
        float r = acc[d][co];
        if (RELU) r = fmaxf(r, 0.f);
        ov[d * COUT + co] = r;
      }
    float* yp = y + ((size_t)(b * HHY + h) * WWX + w) * (DDp * COUT);
#pragma unroll
    for (int i = 0; i < (DDp * COUT) / 4; ++i)
      ((float4*)yp)[i] = ((float4*)ov)[i];
  }
}

// ---------------------------------------------------------------------------
// 8x bilinear upsample, 4 outputs per thread. A 4-aligned output group maps to
// exactly 2 input columns and 2 rows -> 4 loads, 1 float4 store. jax
// half-pixel convention; edge renormalization == index clamp.
// ---------------------------------------------------------------------------
__global__ __launch_bounds__(256) void resize4_k(const float* __restrict__ pred,
                                                 float* __restrict__ out) {
  const int idx = blockIdx.x * 256 + threadIdx.x;   // group id
  const int xg = idx & 511;
  const int y = (idx >> 9) & 1023;
  const int b = idx >> 19;

  const int parity = xg & 1;
  const int m = xg >> 1;
  const int x0 = m - 1 + parity;
  const int x0c = max(x0, 0);
  const int x1c = min(x0 + 1, WWX - 1);
  const float wx0 = (parity ? 0.0625f : 0.5625f);

  const int py = y & 7;
  const int my = y >> 3;
  const int y0 = my - 1 + (py >= 4 ? 1 : 0);
  const float wy = (py >= 4) ? 0.0625f + (py - 4) * 0.125f : 0.5625f + py * 0.125f;
  const int y0c = max(y0, 0);
  const int y1c = min(y0 + 1, HHY - 1);

  const float* pb = pred + (size_t)b * HHY * WWX;
  const float a = pb[y0c * WWX + x0c];
  const float bv = pb[y0c * WWX + x1c];
  const float c = pb[y1c * WWX + x0c];
  const float d = pb[y1c * WWX + x1c];

  const float top0 = a + (bv - a) * wx0;
  const float bot0 = c + (d - c) * wx0;
  const float dtop = (bv - a) * 0.125f;
  const float dbot = (d - c) * 0.125f;

  float4 o;
  o.x = top0 + wy * (bot0 - top0);
  o.y = (top0 + dtop) + wy * ((bot0 + dbot) - (top0 + dtop));
  o.z = (top0 + 2.f * dtop) + wy * ((bot0 + 2.f * dbot) - (top0 + 2.f * dtop));
  o.w = (top0 + 3.f * dtop) + wy * ((bot0 + 3.f * dbot) - (top0 + 3.f * dtop));

  *(float4*)(out + (size_t)idx * 4) = o;
}

// ---------------------------------------------------------------------------
extern "C" void kernel_launch(void* const* d_in, const int* in_sizes, int n_in,
                              void* d_out, int out_size, void* d_ws, size_t ws_size,
                              hipStream_t stream) {
  const float* feat_l = (const float*)d_in[0];
  const float* feat_r = (const float*)d_in[1];
  const float* w0 = (const float*)d_in[2];
  const float* b0 = (const float*)d_in[3];
  const float* w1 = (const float*)d_in[4];
  const float* b1 = (const float*)d_in[5];
  const float* w2 = (const float*)d_in[6];
  const float* b2 = (const float*)d_in[7];
  const float* w3 = (const float*)d_in[8];
  const float* b3 = (const float*)d_in[9];
  const float* wf = (const float*)d_in[10];
  const float* bf = (const float*)d_in[11];
  float* out = (float*)d_out;

  // ws: two ping-pong buffers of [B,H,W,D,4] f32 (100.7 MB each). cost volume
  // ([B,H,W,D], 25 MB) at start of bufA; pred ([B,H,W], 2 MB) at start of
  // bufB after the final fused conv.
  char* ws = (char*)d_ws;
  const size_t buf_bytes = (size_t)BB * HHY * WWX * DDp * 4 * sizeof(float);
  float* bufA = (float*)ws;
  float* bufB = (float*)(ws + buf_bytes);

  dim3 blk(256);
  dim3 grid_row(HHY, BB);
  dim3 grid_conv(HHY * BB);   // 1D, XCD-remapped inside the kernel

  cost_volume_k<<<grid_row, blk, 0, stream>>>(feat_l, feat_r, bufA);
  conv3d_k<1, 4, true, false><<<grid_conv, blk, 0, stream>>>(bufA, w0, b0, bufB);
  conv3d_k<4, 4, true, false><<<grid_conv, blk, 0, stream>>>(bufB, w1, b1, bufA);
  conv3d_k<4, 4, true, false><<<grid_conv, blk, 0, stream>>>(bufA, w2, b2, bufB);
  conv3d_k<4, 4, true, false><<<grid_conv, blk, 0, stream>>>(bufB, w3, b3, bufA);
  conv3d_k<4, 1, false, true><<<grid_conv, blk, 0, stream>>>(bufA, wf, bf, bufB);

  const int ngroups = BB * HOUT * (WOUT / 4);
  resize4_k<<<dim3(ngroups / 256), blk, 0, stream>>>(bufB, out);
}

// Round 7
// 316.466 us; speedup vs baseline: 2.5345x; 1.3017x over previous
//
#include <hip/hip_runtime.h>
#include <cstddef>

// Problem constants (from reference)
#define BB   16
#define HHY  128
#define WWX  256
#define CC   64
#define DDp  12
#define HOUT 1024
#define WOUT 2048

typedef _Float16 hf;                                        // storage type
typedef __fp16 h2 __attribute__((ext_vector_type(2)));      // builtin reg pair

__device__ __forceinline__ h2 u2h(unsigned u) { return __builtin_bit_cast(h2, u); }
__device__ __forceinline__ unsigned pkrtz(float a, float b) {
  return __builtin_bit_cast(unsigned, __builtin_amdgcn_cvt_pkrtz(a, b));
}

#if defined(__has_builtin)
#if __has_builtin(__builtin_amdgcn_fdot2)
#define FDOT2(a, b, c) __builtin_amdgcn_fdot2((a), (b), (c), false)
#endif
#endif
#ifndef FDOT2
#define FDOT2(a, b, c) ((float)(a)[0] * (float)(b)[0] + (float)(a)[1] * (float)(b)[1] + (c))
#endif

// ---------------------------------------------------------------------------
// prep: convert conv weights to fp16, repacked [tap27][co][ci] so the ci pairs
// consumed by v_dot2_f32_f16 are contiguous. w1,w2,w3: 432 each; wf: 108.
// ---------------------------------------------------------------------------
__global__ __launch_bounds__(256) void prep_k(const float* __restrict__ w1,
                                              const float* __restrict__ w2,
                                              const float* __restrict__ w3,
                                              const float* __restrict__ wf,
                                              hf* __restrict__ o) {
  const int t = threadIdx.x;
  for (int i = t; i < 432; i += 256) {
    const int t27 = i >> 4;
    const int ci = (i >> 2) & 3;
    const int co = i & 3;
    const int dst = (t27 * 4 + co) * 4 + ci;
    o[dst]       = (hf)w1[i];
    o[432 + dst] = (hf)w2[i];
    o[864 + dst] = (hf)w3[i];
  }
  for (int i = t; i < 108; i += 256) o[1296 + i] = (hf)wf[i];  // [t27][ci], COUT=1
}

// ---------------------------------------------------------------------------
// Kernel 1: cost volume (f32 out). Block = one (b,h) row, thread = w. R staged
// in LDS (16-ch chunks = one 64B line per w), L read direct to registers.
// Per-block PHASE STAGGER on the chunk order: blocks on a CU start at
// different channel chunks -> load/compute phases of co-resident blocks
// overlap instead of phase-locking (r5: 118us invariant to occupancy).
// ---------------------------------------------------------------------------
#define CCH 16
#define LST 20

__global__ __launch_bounds__(256) void cost_volume_k(const float* __restrict__ L,
                                                     const float* __restrict__ R,
                                                     float* __restrict__ cost) {
  __shared__ float lsR[WWX * LST];   // 20 KB
  const int t = threadIdx.x;
  const int h = blockIdx.x;
  const int b = blockIdx.y;
  const size_t rowbase = ((size_t)(b * HHY + h)) * WWX;
  const float* Lrow = L + rowbase * CC;
  const float* Rrow = R + rowbase * CC;

  float acc[DDp];
#pragma unroll
  for (int d = 0; d < DDp; ++d) acc[d] = 0.f;

  const int ph = (h ^ (b << 1)) & 3;   // per-block phase offset
#pragma unroll
  for (int p = 0; p < 4; ++p) {
    const int c0 = ((p + ph) & 3) * CCH;
    __syncthreads();  // previous chunk's readers done
#pragma unroll
    for (int j = 0; j < 4; ++j) {
      const int i = t + 256 * j;     // float4 id in [0,1024)
      const int w = i >> 2;
      const int r4 = (i & 3) << 2;
      *(float4*)(&lsR[w * LST + r4]) =
          *(const float4*)(Rrow + (size_t)w * CC + c0 + r4);
    }
    __syncthreads();

    float l[CCH];
#pragma unroll
    for (int k = 0; k < CCH / 4; ++k)
      ((float4*)l)[k] = *(const float4*)(Lrow + (size_t)t * CC + c0 + 4 * k);

    float sl = 0.f;
#pragma unroll
    for (int k = 0; k < CCH; ++k) sl += fabsf(l[k]);

#pragma unroll
    for (int d = 0; d < DDp; ++d) {
      if (t >= d) {
        const float* rp = &lsR[(t - d) * LST];
        float a = 0.f;
#pragma unroll
        for (int k = 0; k < CCH / 4; ++k) {
          const float4 r4 = *(const float4*)(rp + 4 * k);
          a += fabsf(l[4 * k + 0] - r4.x) + fabsf(l[4 * k + 1] - r4.y) +
               fabsf(l[4 * k + 2] - r4.z) + fabsf(l[4 * k + 3] - r4.w);
        }
        acc[d] += a;
      } else {
        acc[d] += sl;
      }
    }
  }

  float* cp = cost + (rowbase + t) * DDp;
#pragma unroll
  for (int d = 0; d < DDp; d += 4)
    *(float4*)(cp + d) = make_float4(acc[d], acc[d + 1], acc[d + 2], acc[d + 3]);
}

// ---------------------------------------------------------------------------
// conv0: 3x3x3, CIN=1 (f32 cost) -> COUT=4 (fp16 out). Block = one (b,h) row
// (XCD h-remap), thread = w. Row staged f32 in LDS stride 20; weights (108 f)
// wave-uniform global loads; fp16 pack on store (halves write traffic).
// ---------------------------------------------------------------------------
__global__ __launch_bounds__(256) void conv0_k(const float* __restrict__ x,
                                               const float* __restrict__ wt,
                                               const float* __restrict__ bs,
                                               hf* __restrict__ y) {
  constexpr int S = 20;
  __shared__ float ls[WWX * S];   // 20 KB
  const int t = threadIdx.x;
  const int id = blockIdx.x;
  const int h = ((id & 7) << 4) | ((id >> 3) & 15);  // XCD-contiguous h chunks
  const int b = id >> 7;

  float acc[DDp][4];
#pragma unroll
  for (int co = 0; co < 4; ++co) {
    const float bv = bs[co];
#pragma unroll
    for (int d = 0; d < DDp; ++d) acc[d][co] = bv;
  }

#pragma unroll
  for (int kh = 0; kh < 3; ++kh) {
    const int hh = h + kh - 1;
    if (hh < 0 || hh >= HHY) continue;  // block-uniform

    __syncthreads();
    const float* xr = x + ((size_t)(b * HHY + hh) * WWX) * DDp;
#pragma unroll
    for (int j = 0; j < 3; ++j) {
      const int fi4 = t + 256 * j;     // [0,768)
      const int w_ = fi4 / 3;
      const int k_ = fi4 - w_ * 3;
      *(float4*)(&ls[w_ * S + k_ * 4]) = ((const float4*)xr)[fi4];
    }
    __syncthreads();

#pragma unroll
    for (int kw = 0; kw < 3; ++kw) {
      const int ww = t + kw - 1;
      if (ww < 0 || ww >= WWX) continue;
      const float* lp = &ls[ww * S];

      const float* wp = wt + (size_t)(kh * 3 + kw) * 12;
      float wr[12];
#pragma unroll
      for (int i = 0; i < 12; ++i) wr[i] = wp[i];

      float v[DDp];
#pragma unroll
      for (int k = 0; k < 3; ++k)
        ((float4*)v)[k] = *(const float4*)(lp + 4 * k);
#pragma unroll
      for (int vo = 0; vo < DDp; ++vo)
#pragma unroll
        for (int kd = 0; kd < 3; ++kd) {
          const int d = vo + 1 - kd;
          if (d < 0 || d >= DDp) continue;
#pragma unroll
          for (int co = 0; co < 4; ++co)
            acc[d][co] += v[vo] * wr[kd * 4 + co];
        }
    }
  }

  unsigned ov[DDp * 2];
#pragma unroll
  for (int d = 0; d < DDp; ++d) {
    ov[d * 2]     = pkrtz(fmaxf(acc[d][0], 0.f), fmaxf(acc[d][1], 0.f));
    ov[d * 2 + 1] = pkrtz(fmaxf(acc[d][2], 0.f), fmaxf(acc[d][3], 0.f));
  }
  uint4* yp = (uint4*)(y + ((size_t)(b * HHY + h) * WWX + t) * (DDp * 4));
#pragma unroll
  for (int i = 0; i < 6; ++i) yp[i] = ((uint4*)ov)[i];
}

// ---------------------------------------------------------------------------
// Mid/final conv3d 3x3x3, CIN=4, fp16 activations [B,H,W,D,4], f32 accumulate
// via v_dot2_f32_f16 (2 MAC/instr). Block = one (b,h) row (XCD h-remap),
// thread = w. Rows staged fp16 in LDS (52-half stride = 26 uints; 26.6 KB ->
// 6 blocks/CU). Weights: fp16 repacked [tap][co][ci] -> wave-uniform uint
// scalar loads feed fdot2 directly. FUSE_SM: COUT=1 + softmax + regression.
// ---------------------------------------------------------------------------
template <int COUT, bool FUSE_SM>
__global__ __launch_bounds__(256) void convh_k(const hf* __restrict__ x,
                                               const hf* __restrict__ wh,
                                               const float* __restrict__ bs,
                                               void* __restrict__ yv) {
  constexpr int DCH = DDp * 4;        // 48 halves per w
  constexpr int SU  = 26;             // LDS stride per w in uints (52 halves)
  __shared__ unsigned lsu[WWX * SU];  // 26624 B

  const int t = threadIdx.x;
  const int id = blockIdx.x;
  const int h = ((id & 7) << 4) | ((id >> 3) & 15);
  const int b = id >> 7;

  float acc[DDp][COUT];
#pragma unroll
  for (int co = 0; co < COUT; ++co) {
    const float bv = bs[co];
#pragma unroll
    for (int d = 0; d < DDp; ++d) acc[d][co] = bv;
  }

  const unsigned* whu = (const unsigned*)wh;

#pragma unroll
  for (int kh = 0; kh < 3; ++kh) {
    const int hh = h + kh - 1;
    if (hh < 0 || hh >= HHY) continue;  // block-uniform

    __syncthreads();
    const uint4* xr = (const uint4*)(x + (size_t)(b * HHY + hh) * WWX * DCH);
#pragma unroll
    for (int j = 0; j < 6; ++j) {
      const int fi4 = t + 256 * j;     // [0,1536)
      const int w_ = fi4 / 6;
      const int k_ = fi4 - w_ * 6;
      const uint4 v = xr[fi4];
      unsigned* dst = &lsu[w_ * SU + k_ * 4];
      *(uint2*)(dst)     = make_uint2(v.x, v.y);
      *(uint2*)(dst + 2) = make_uint2(v.z, v.w);
    }
    __syncthreads();

#pragma unroll
    for (int kw = 0; kw < 3; ++kw) {
      const int ww = t + kw - 1;
      if (ww < 0 || ww >= WWX) continue;  // divergent only at row edges

      // per-tap fp16 weights, wave-uniform scalar loads
      unsigned w01[3][COUT], w23[3][COUT];
      const int tap3 = (kh * 3 + kw) * 3;
#pragma unroll
      for (int kd = 0; kd < 3; ++kd)
#pragma unroll
        for (int co = 0; co < COUT; ++co) {
          const int u0 = ((tap3 + kd) * COUT + co) * 2;
          w01[kd][co] = whu[u0];
          w23[kd][co] = whu[u0 + 1];
        }

      const unsigned* lp = &lsu[ww * SU];
#pragma unroll
      for (int vo = 0; vo < DDp; ++vo) {
        const uint2 xu = *(const uint2*)(lp + vo * 2);
        const h2 x01 = u2h(xu.x), x23 = u2h(xu.y);
#pragma unroll
        for (int kd = 0; kd < 3; ++kd) {
          const int d = vo + 1 - kd;
          if (d < 0 || d >= DDp) continue;
#pragma unroll
          for (int co = 0; co < COUT; ++co)
            acc[d][co] = FDOT2(x01, u2h(w01[kd][co]),
                         FDOT2(x23, u2h(w23[kd][co]), acc[d][co]));
        }
      }
    }
  }

  if constexpr (FUSE_SM) {
    float* y = (float*)yv;
    float mn = acc[0][0];
#pragma unroll
    for (int d = 1; d < DDp; ++d) mn = fminf(mn, acc[d][0]);
    float s = 0.f, sw = 0.f;
#pragma unroll
    for (int d = 0; d < DDp; ++d) {
      const float e = __expf(mn - acc[d][0]);
      s += e;
      sw += e * (float)d;
    }
    y[(size_t)(b * HHY + h) * WWX + t] = sw / s;
  } else {
    hf* y = (hf*)yv;
    unsigned ov[DDp * 2];
#pragma unroll
    for (int d = 0; d < DDp; ++d) {
      ov[d * 2]     = pkrtz(fmaxf(acc[d][0], 0.f), fmaxf(acc[d][1 % COUT], 0.f));
      ov[d * 2 + 1] = pkrtz(fmaxf(acc[d][2 % COUT], 0.f), fmaxf(acc[d][3 % COUT], 0.f));
    }
    uint4* yp = (uint4*)(y + ((size_t)(b * HHY + h) * WWX + t) * DCH);
#pragma unroll
    for (int i = 0; i < 6; ++i) yp[i] = ((uint4*)ov)[i];
  }
}

// ---------------------------------------------------------------------------
// 8x bilinear upsample, 4 outputs per thread (2 input cols x 2 rows -> 4 loads,
// 1 float4 store). jax half-pixel convention; edge renorm == index clamp.
// ---------------------------------------------------------------------------
__global__ __launch_bounds__(256) void resize4_k(const float* __restrict__ pred,
                                                 float* __restrict__ out) {
  const int idx = blockIdx.x * 256 + threadIdx.x;
  const int xg = idx & 511;
  const int y = (idx >> 9) & 1023;
  const int b = idx >> 19;

  const int parity = xg & 1;
  const int m = xg >> 1;
  const int x0 = m - 1 + parity;
  const int x0c = max(x0, 0);
  const int x1c = min(x0 + 1, WWX - 1);
  const float wx0 = (parity ? 0.0625f : 0.5625f);

  const int py = y & 7;
  const int my = y >> 3;
  const int y0 = my - 1 + (py >= 4 ? 1 : 0);
  const float wy = (py >= 4) ? 0.0625f + (py - 4) * 0.125f : 0.5625f + py * 0.125f;
  const int y0c = max(y0, 0);
  const int y1c = min(y0 + 1, HHY - 1);

  const float* pb = pred + (size_t)b * HHY * WWX;
  const float a = pb[y0c * WWX + x0c];
  const float bv = pb[y0c * WWX + x1c];
  const float c = pb[y1c * WWX + x0c];
  const float d = pb[y1c * WWX + x1c];

  const float top0 = a + (bv - a) * wx0;
  const float bot0 = c + (d - c) * wx0;
  const float dtop = (bv - a) * 0.125f;
  const float dbot = (d - c) * 0.125f;

  float4 o;
  o.x = top0 + wy * (bot0 - top0);
  o.y = (top0 + dtop) + wy * ((bot0 + dbot) - (top0 + dtop));
  o.z = (top0 + 2.f * dtop) + wy * ((bot0 + 2.f * dbot) - (top0 + 2.f * dtop));
  o.w = (top0 + 3.f * dtop) + wy * ((bot0 + 3.f * dbot) - (top0 + 3.f * dtop));

  *(float4*)(out + (size_t)idx * 4) = o;
}

// ---------------------------------------------------------------------------
extern "C" void kernel_launch(void* const* d_in, const int* in_sizes, int n_in,
                              void* d_out, int out_size, void* d_ws, size_t ws_size,
                              hipStream_t stream) {
  const float* feat_l = (const float*)d_in[0];
  const float* feat_r = (const float*)d_in[1];
  const float* w0 = (const float*)d_in[2];
  const float* b0 = (const float*)d_in[3];
  const float* w1 = (const float*)d_in[4];
  const float* b1 = (const float*)d_in[5];
  const float* w2 = (const float*)d_in[6];
  const float* b2 = (const float*)d_in[7];
  const float* w3 = (const float*)d_in[8];
  const float* b3 = (const float*)d_in[9];
  const float* wf = (const float*)d_in[10];
  const float* bf = (const float*)d_in[11];
  float* out = (float*)d_out;

  // ws layout: A,B = fp16 activation ping-pong [B,H,W,D,4] (50.3 MB each);
  // C = f32 cost volume (25.2 MB); P = f32 pred (2.1 MB); Wh = fp16 weights.
  char* ws = (char*)d_ws;
  hf*    A  = (hf*)ws;
  hf*    Bf = (hf*)(ws + 50331648);
  float* C  = (float*)(ws + 100663296);
  float* P  = (float*)(ws + 125829120);
  hf*    Wh = (hf*)(ws + 127926272);

  dim3 blk(256);
  prep_k<<<dim3(1), blk, 0, stream>>>(w1, w2, w3, wf, Wh);
  cost_volume_k<<<dim3(HHY, BB), blk, 0, stream>>>(feat_l, feat_r, C);
  conv0_k<<<dim3(HHY * BB), blk, 0, stream>>>(C, w0, b0, A);
  convh_k<4, false><<<dim3(HHY * BB), blk, 0, stream>>>(A,  Wh,        b1, Bf);
  convh_k<4, false><<<dim3(HHY * BB), blk, 0, stream>>>(Bf, Wh + 432,  b2, A);
  convh_k<4, false><<<dim3(HHY * BB), blk, 0, stream>>>(A,  Wh + 864,  b3, Bf);
  convh_k<1, true ><<<dim3(HHY * BB), blk, 0, stream>>>(Bf, Wh + 1296, bf, P);

  const int ngroups = BB * HOUT * (WOUT / 4);
  resize4_k<<<dim3(ngroups / 256), blk, 0, stream>>>(P, out);
}

// Round 9
// 299.454 us; speedup vs baseline: 2.6785x; 1.0568x over previous
//
#include <hip/hip_runtime.h>
#include <cstddef>

// Problem constants (from reference)
#define BB   16
#define HHY  128
#define WWX  256
#define CC   64
#define DDp  12
#define HOUT 1024
#define WOUT 2048

typedef _Float16 hf;                                        // storage type
typedef __fp16 h2 __attribute__((ext_vector_type(2)));      // builtin reg pair

__device__ __forceinline__ h2 u2h(unsigned u) { return __builtin_bit_cast(h2, u); }
__device__ __forceinline__ unsigned pkrtz(float a, float b) {
  return __builtin_bit_cast(unsigned, __builtin_amdgcn_cvt_pkrtz(a, b));
}

#if defined(__has_builtin)
#if __has_builtin(__builtin_amdgcn_fdot2)
#define FDOT2(a, b, c) __builtin_amdgcn_fdot2((a), (b), (c), false)
#endif
#endif
#ifndef FDOT2
#define FDOT2(a, b, c) ((float)(a)[0] * (float)(b)[0] + (float)(a)[1] * (float)(b)[1] + (c))
#endif

// |a-b| dot (1,1) accumulated into c, all on packed fp16 pairs (f32 accum):
// v_pk_add_f16(neg) + v_and_b32 + v_dot2_f32_f16 = 3 VALU per 2 channels.
__device__ __forceinline__ float adot(unsigned lu, unsigned ru, float c) {
  const h2 d = u2h(lu) - u2h(ru);
  const unsigned au = __builtin_bit_cast(unsigned, d) & 0x7FFF7FFFu;
  return FDOT2(u2h(au), u2h(0x3C003C00u), c);
}

// ---------------------------------------------------------------------------
// prep: convert conv weights to fp16, repacked [tap27][co][ci] so the ci pairs
// consumed by v_dot2_f32_f16 are contiguous. w1,w2,w3: 432 each; wf: 108.
// ---------------------------------------------------------------------------
__global__ __launch_bounds__(256) void prep_k(const float* __restrict__ w1,
                                              const float* __restrict__ w2,
                                              const float* __restrict__ w3,
                                              const float* __restrict__ wf,
                                              hf* __restrict__ o) {
  const int t = threadIdx.x;
  for (int i = t; i < 432; i += 256) {
    const int t27 = i >> 4;
    const int ci = (i >> 2) & 3;
    const int co = i & 3;
    const int dst = (t27 * 4 + co) * 4 + ci;
    o[dst]       = (hf)w1[i];
    o[432 + dst] = (hf)w2[i];
    o[864 + dst] = (hf)w3[i];
  }
  for (int i = t; i < 108; i += 256) o[1296 + i] = (hf)wf[i];  // [t27][ci], COUT=1
}

// ---------------------------------------------------------------------------
// Kernel 1: cost volume (f32 out). cost[b,h,w,d] = sum_c |L[b,h,w,c]-R[b,h,w-d,c]|
// (zero-pad shift: w<d contributes sum_c |L|).
// SINGLE-BARRIER design (r7 post-mortem: 8 barrier-drains/block made 118us
// invariant to occupancy). Whole R row staged ONCE as fp16 pairs in LDS;
// L kept in 32 packed-h2 registers (per-thread 64B-line loads, fully
// consumed). One __syncthreads, then pure compute.
// RSTRIDE = 36 dwords/row: 32 DATA dwords (64ch x fp16) + 4 pad. (r8 bug:
// stride 20 < 32 data overlapped adjacent rows -> corrupted LDS.) Start bank
// 4t mod 32 has period 8 -> each 16-lane b128 phase is 2-way (free, m136).
// ---------------------------------------------------------------------------
#define RSTRIDE 36

__global__ __launch_bounds__(256) void cost_volume_k(const float* __restrict__ L,
                                                     const float* __restrict__ R,
                                                     float* __restrict__ cost) {
  __shared__ unsigned lsR[WWX * RSTRIDE];   // 36 KB
  const int t = threadIdx.x;
  const int h = blockIdx.x;
  const int b = blockIdx.y;
  const size_t rowbase = ((size_t)(b * HHY + h)) * WWX;
  const float* Lrow = L + rowbase * CC;
  const float* Rrow = R + rowbase * CC;

  // Stage R: coalesced float4 loads (16 lanes/row), convert to fp16 pairs.
#pragma unroll
  for (int j = 0; j < 16; ++j) {
    const int fi = t + 256 * j;        // float4 id in [0,4096)
    const int w = fi >> 4;
    const int f4 = fi & 15;
    const float4 v = *(const float4*)(Rrow + (size_t)w * CC + 4 * f4);
    *(uint2*)(&lsR[w * RSTRIDE + f4 * 2]) =
        make_uint2(pkrtz(v.x, v.y), pkrtz(v.z, v.w));
  }

  // L: thread t owns row t; 16 float4 = 4 full 64B lines, converted to h2.
  unsigned lh[32];
#pragma unroll
  for (int k = 0; k < 16; ++k) {
    const float4 v = *(const float4*)(Lrow + (size_t)t * CC + 4 * k);
    lh[2 * k]     = pkrtz(v.x, v.y);
    lh[2 * k + 1] = pkrtz(v.z, v.w);
  }

  // zero-pad case value: sum |l| via the same fp16 path (consistent rounding)
  float sl = 0.f;
#pragma unroll
  for (int i = 0; i < 32; ++i) sl = adot(lh[i], 0u, sl);

  __syncthreads();   // the ONLY barrier

  float acc[DDp];
#pragma unroll
  for (int d = 0; d < DDp; ++d) {
    if (t >= d) {
      const unsigned* rp = &lsR[(t - d) * RSTRIDE];
      float a = 0.f;
#pragma unroll
      for (int k = 0; k < 8; ++k) {     // 8 x b128 = 64 channels
        const uint4 r = *(const uint4*)(rp + 4 * k);
        a = adot(lh[4 * k + 0], r.x, a);
        a = adot(lh[4 * k + 1], r.y, a);
        a = adot(lh[4 * k + 2], r.z, a);
        a = adot(lh[4 * k + 3], r.w, a);
      }
      acc[d] = a;
    } else {
      acc[d] = sl;
    }
  }

  float* cp = cost + (rowbase + t) * DDp;
#pragma unroll
  for (int d = 0; d < DDp; d += 4)
    *(float4*)(cp + d) = make_float4(acc[d], acc[d + 1], acc[d + 2], acc[d + 3]);
}

// ---------------------------------------------------------------------------
// conv0: 3x3x3, CIN=1 (f32 cost) -> COUT=4 (fp16 out). Block = one (b,h) row
// (XCD h-remap), thread = w. Row staged f32 in LDS stride 20; weights (108 f)
// wave-uniform global loads; fp16 pack on store (halves write traffic).
// ---------------------------------------------------------------------------
__global__ __launch_bounds__(256) void conv0_k(const float* __restrict__ x,
                                               const float* __restrict__ wt,
                                               const float* __restrict__ bs,
                                               hf* __restrict__ y) {
  constexpr int S = 20;
  __shared__ float ls[WWX * S];   // 20 KB
  const int t = threadIdx.x;
  const int id = blockIdx.x;
  const int h = ((id & 7) << 4) | ((id >> 3) & 15);  // XCD-contiguous h chunks
  const int b = id >> 7;

  float acc[DDp][4];
#pragma unroll
  for (int co = 0; co < 4; ++co) {
    const float bv = bs[co];
#pragma unroll
    for (int d = 0; d < DDp; ++d) acc[d][co] = bv;
  }

#pragma unroll
  for (int kh = 0; kh < 3; ++kh) {
    const int hh = h + kh - 1;
    if (hh < 0 || hh >= HHY) continue;  // block-uniform

    __syncthreads();
    const float* xr = x + ((size_t)(b * HHY + hh) * WWX) * DDp;
#pragma unroll
    for (int j = 0; j < 3; ++j) {
      const int fi4 = t + 256 * j;     // [0,768)
      const int w_ = fi4 / 3;
      const int k_ = fi4 - w_ * 3;
      *(float4*)(&ls[w_ * S + k_ * 4]) = ((const float4*)xr)[fi4];
    }
    __syncthreads();

#pragma unroll
    for (int kw = 0; kw < 3; ++kw) {
      const int ww = t + kw - 1;
      if (ww < 0 || ww >= WWX) continue;
      const float* lp = &ls[ww * S];

      const float* wp = wt + (size_t)(kh * 3 + kw) * 12;
      float wr[12];
#pragma unroll
      for (int i = 0; i < 12; ++i) wr[i] = wp[i];

      float v[DDp];
#pragma unroll
      for (int k = 0; k < 3; ++k)
        ((float4*)v)[k] = *(const float4*)(lp + 4 * k);
#pragma unroll
      for (int vo = 0; vo < DDp; ++vo)
#pragma unroll
        for (int kd = 0; kd < 3; ++kd) {
          const int d = vo + 1 - kd;
          if (d < 0 || d >= DDp) continue;
#pragma unroll
          for (int co = 0; co < 4; ++co)
            acc[d][co] += v[vo] * wr[kd * 4 + co];
        }
    }
  }

  unsigned ov[DDp * 2];
#pragma unroll
  for (int d = 0; d < DDp; ++d) {
    ov[d * 2]     = pkrtz(fmaxf(acc[d][0], 0.f), fmaxf(acc[d][1], 0.f));
    ov[d * 2 + 1] = pkrtz(fmaxf(acc[d][2], 0.f), fmaxf(acc[d][3], 0.f));
  }
  uint4* yp = (uint4*)(y + ((size_t)(b * HHY + h) * WWX + t) * (DDp * 4));
#pragma unroll
  for (int i = 0; i < 6; ++i) yp[i] = ((uint4*)ov)[i];
}

// ---------------------------------------------------------------------------
// Mid/final conv3d 3x3x3, CIN=4, fp16 activations [B,H,W,D,4], f32 accumulate
// via v_dot2_f32_f16 (2 MAC/instr). Block = one (b,h) row (XCD h-remap),
// thread = w. Rows staged fp16 in LDS (52-half stride = 26 uints; 26.6 KB ->
// 6 blocks/CU). Weights: fp16 repacked [tap][co][ci] -> wave-uniform uint
// scalar loads feed fdot2 directly. FUSE_SM: COUT=1 + softmax + regression.
// ---------------------------------------------------------------------------
template <int COUT, bool FUSE_SM>
__global__ __launch_bounds__(256) void convh_k(const hf* __restrict__ x,
                                               const hf* __restrict__ wh,
                                               const float* __restrict__ bs,
                                               void* __restrict__ yv) {
  constexpr int DCH = DDp * 4;        // 48 halves per w
  constexpr int SU  = 26;             // LDS stride per w in uints (52 halves)
  __shared__ unsigned lsu[WWX * SU];  // 26624 B

  const int t = threadIdx.x;
  const int id = blockIdx.x;
  const int h = ((id & 7) << 4) | ((id >> 3) & 15);
  const int b = id >> 7;

  float acc[DDp][COUT];
#pragma unroll
  for (int co = 0; co < COUT; ++co) {
    const float bv = bs[co];
#pragma unroll
    for (int d = 0; d < DDp; ++d) acc[d][co] = bv;
  }

  const unsigned* whu = (const unsigned*)wh;

#pragma unroll
  for (int kh = 0; kh < 3; ++kh) {
    const int hh = h + kh - 1;
    if (hh < 0 || hh >= HHY) continue;  // block-uniform

    __syncthreads();
    const uint4* xr = (const uint4*)(x + (size_t)(b * HHY + hh) * WWX * DCH);
#pragma unroll
    for (int j = 0; j < 6; ++j) {
      const int fi4 = t + 256 * j;     // [0,1536)
      const int w_ = fi4 / 6;
      const int k_ = fi4 - w_ * 6;
      const uint4 v = xr[fi4];
      unsigned* dst = &lsu[w_ * SU + k_ * 4];
      *(uint2*)(dst)     = make_uint2(v.x, v.y);
      *(uint2*)(dst + 2) = make_uint2(v.z, v.w);
    }
    __syncthreads();

#pragma unroll
    for (int kw = 0; kw < 3; ++kw) {
      const int ww = t + kw - 1;
      if (ww < 0 || ww >= WWX) continue;  // divergent only at row edges

      // per-tap fp16 weights, wave-uniform scalar loads
      unsigned w01[3][COUT], w23[3][COUT];
      const int tap3 = (kh * 3 + kw) * 3;
#pragma unroll
      for (int kd = 0; kd < 3; ++kd)
#pragma unroll
        for (int co = 0; co < COUT; ++co) {
          const int u0 = ((tap3 + kd) * COUT + co) * 2;
          w01[kd][co] = whu[u0];
          w23[kd][co] = whu[u0 + 1];
        }

      const unsigned* lp = &lsu[ww * SU];
#pragma unroll
      for (int vo = 0; vo < DDp; ++vo) {
        const uint2 xu = *(const uint2*)(lp + vo * 2);
        const h2 x01 = u2h(xu.x), x23 = u2h(xu.y);
#pragma unroll
        for (int kd = 0; kd < 3; ++kd) {
          const int d = vo + 1 - kd;
          if (d < 0 || d >= DDp) continue;
#pragma unroll
          for (int co = 0; co < COUT; ++co)
            acc[d][co] = FDOT2(x01, u2h(w01[kd][co]),
                         FDOT2(x23, u2h(w23[kd][co]), acc[d][co]));
        }
      }
    }
  }

  if constexpr (FUSE_SM) {
    float* y = (float*)yv;
    float mn = acc[0][0];
#pragma unroll
    for (int d = 1; d < DDp; ++d) mn = fminf(mn, acc[d][0]);
    float s = 0.f, sw = 0.f;
#pragma unroll
    for (int d = 0; d < DDp; ++d) {
      const float e = __expf(mn - acc[d][0]);
      s += e;
      sw += e * (float)d;
    }
    y[(size_t)(b * HHY + h) * WWX + t] = sw / s;
  } else {
    hf* y = (hf*)yv;
    unsigned ov[DDp * 2];
#pragma unroll
    for (int d = 0; d < DDp; ++d) {
      ov[d * 2]     = pkrtz(fmaxf(acc[d][0], 0.f), fmaxf(acc[d][1 % COUT], 0.f));
      ov[d * 2 + 1] = pkrtz(fmaxf(acc[d][2 % COUT], 0.f), fmaxf(acc[d][3 % COUT], 0.f));
    }
    uint4* yp = (uint4*)(y + ((size_t)(b * HHY + h) * WWX + t) * DCH);
#pragma unroll
    for (int i = 0; i < 6; ++i) yp[i] = ((uint4*)ov)[i];
  }
}

// ---------------------------------------------------------------------------
// 8x bilinear upsample, 4 outputs per thread (2 input cols x 2 rows -> 4 loads,
// 1 float4 store). jax half-pixel convention; edge renorm == index clamp.
// ---------------------------------------------------------------------------
__global__ __launch_bounds__(256) void resize4_k(const float* __restrict__ pred,
                                                 float* __restrict__ out) {
  const int idx = blockIdx.x * 256 + threadIdx.x;
  const int xg = idx & 511;
  const int y = (idx >> 9) & 1023;
  const int b = idx >> 19;

  const int parity = xg & 1;
  const int m = xg >> 1;
  const int x0 = m - 1 + parity;
  const int x0c = max(x0, 0);
  const int x1c = min(x0 + 1, WWX - 1);
  const float wx0 = (parity ? 0.0625f : 0.5625f);

  const int py = y & 7;
  const int my = y >> 3;
  const int y0 = my - 1 + (py >= 4 ? 1 : 0);
  const float wy = (py >= 4) ? 0.0625f + (py - 4) * 0.125f : 0.5625f + py * 0.125f;
  const int y0c = max(y0, 0);
  const int y1c = min(y0 + 1, HHY - 1);

  const float* pb = pred + (size_t)b * HHY * WWX;
  const float a = pb[y0c * WWX + x0c];
  const float bv = pb[y0c * WWX + x1c];
  const float c = pb[y1c * WWX + x0c];
  const float d = pb[y1c * WWX + x1c];

  const float top0 = a + (bv - a) * wx0;
  const float bot0 = c + (d - c) * wx0;
  const float dtop = (bv - a) * 0.125f;
  const float dbot = (d - c) * 0.125f;

  float4 o;
  o.x = top0 + wy * (bot0 - top0);
  o.y = (top0 + dtop) + wy * ((bot0 + dbot) - (top0 + dtop));
  o.z = (top0 + 2.f * dtop) + wy * ((bot0 + 2.f * dbot) - (top0 + 2.f * dtop));
  o.w = (top0 + 3.f * dtop) + wy * ((bot0 + 3.f * dbot) - (top0 + 3.f * dtop));

  *(float4*)(out + (size_t)idx * 4) = o;
}

// ---------------------------------------------------------------------------
extern "C" void kernel_launch(void* const* d_in, const int* in_sizes, int n_in,
                              void* d_out, int out_size, void* d_ws, size_t ws_size,
                              hipStream_t stream) {
  const float* feat_l = (const float*)d_in[0];
  const float* feat_r = (const float*)d_in[1];
  const float* w0 = (const float*)d_in[2];
  const float* b0 = (const float*)d_in[3];
  const float* w1 = (const float*)d_in[4];
  const float* b1 = (const float*)d_in[5];
  const float* w2 = (const float*)d_in[6];
  const float* b2 = (const float*)d_in[7];
  const float* w3 = (const float*)d_in[8];
  const float* b3 = (const float*)d_in[9];
  const float* wf = (const float*)d_in[10];
  const float* bf = (const float*)d_in[11];
  float* out = (float*)d_out;

  // ws layout: A,B = fp16 activation ping-pong [B,H,W,D,4] (50.3 MB each);
  // C = f32 cost volume (25.2 MB); P = f32 pred (2.1 MB); Wh = fp16 weights.
  char* ws = (char*)d_ws;
  hf*    A  = (hf*)ws;
  hf*    Bf = (hf*)(ws + 50331648);
  float* C  = (float*)(ws + 100663296);
  float* P  = (float*)(ws + 125829120);
  hf*    Wh = (hf*)(ws + 127926272);

  dim3 blk(256);
  prep_k<<<dim3(1), blk, 0, stream>>>(w1, w2, w3, wf, Wh);
  cost_volume_k<<<dim3(HHY, BB), blk, 0, stream>>>(feat_l, feat_r, C);
  conv0_k<<<dim3(HHY * BB), blk, 0, stream>>>(C, w0, b0, A);
  convh_k<4, false><<<dim3(HHY * BB), blk, 0, stream>>>(A,  Wh,        b1, Bf);
  convh_k<4, false><<<dim3(HHY * BB), blk, 0, stream>>>(Bf, Wh + 432,  b2, A);
  convh_k<4, false><<<dim3(HHY * BB), blk, 0, stream>>>(A,  Wh + 864,  b3, Bf);
  convh_k<1, true ><<<dim3(HHY * BB), blk, 0, stream>>>(Bf, Wh + 1296, bf, P);

  const int ngroups = BB * HOUT * (WOUT / 4);
  resize4_k<<<dim3(ngroups / 256), blk, 0, stream>>>(P, out);
}

// Round 10
// 296.758 us; speedup vs baseline: 2.7028x; 1.0091x over previous
//
#include <hip/hip_runtime.h>
#include <cstddef>

// Problem constants (from reference)
#define BB   16
#define HHY  128
#define WWX  256
#define CC   64
#define DDp  12
#define HOUT 1024
#define WOUT 2048

typedef _Float16 hf;                                        // storage type
typedef __fp16 h2 __attribute__((ext_vector_type(2)));      // builtin reg pair

__device__ __forceinline__ h2 u2h(unsigned u) { return __builtin_bit_cast(h2, u); }
__device__ __forceinline__ unsigned pkrtz(float a, float b) {
  return __builtin_bit_cast(unsigned, __builtin_amdgcn_cvt_pkrtz(a, b));
}

#if defined(__has_builtin)
#if __has_builtin(__builtin_amdgcn_fdot2)
#define FDOT2(a, b, c) __builtin_amdgcn_fdot2((a), (b), (c), false)
#endif
#endif
#ifndef FDOT2
#define FDOT2(a, b, c) ((float)(a)[0] * (float)(b)[0] + (float)(a)[1] * (float)(b)[1] + (c))
#endif

// |a-b| dot (1,1) accumulated into c, all on packed fp16 pairs (f32 accum):
// v_pk_add_f16(neg) + v_and_b32 + v_dot2_f32_f16 = 3 VALU per 2 channels.
__device__ __forceinline__ float adot(unsigned lu, unsigned ru, float c) {
  const h2 d = u2h(lu) - u2h(ru);
  const unsigned au = __builtin_bit_cast(unsigned, d) & 0x7FFF7FFFu;
  return FDOT2(u2h(au), u2h(0x3C003C00u), c);
}

// ---------------------------------------------------------------------------
// prep: convert conv weights to fp16, repacked [tap27][co][ci] so the ci pairs
// consumed by v_dot2_f32_f16 are contiguous. w1,w2,w3: 432 each; wf: 108.
// ---------------------------------------------------------------------------
__global__ __launch_bounds__(256) void prep_k(const float* __restrict__ w1,
                                              const float* __restrict__ w2,
                                              const float* __restrict__ w3,
                                              const float* __restrict__ wf,
                                              hf* __restrict__ o) {
  const int t = threadIdx.x;
  for (int i = t; i < 432; i += 256) {
    const int t27 = i >> 4;
    const int ci = (i >> 2) & 3;
    const int co = i & 3;
    const int dst = (t27 * 4 + co) * 4 + ci;
    o[dst]       = (hf)w1[i];
    o[432 + dst] = (hf)w2[i];
    o[864 + dst] = (hf)w3[i];
  }
  for (int i = t; i < 108; i += 256) o[1296 + i] = (hf)wf[i];  // [t27][ci], COUT=1
}

// ---------------------------------------------------------------------------
// Kernel 1: cost volume (f32 out). cost[b,h,w,d] = sum_c |L[b,h,w,c]-R[b,h,w-d,c]|
// (zero-pad shift: w<d contributes sum_c |L|).
// Single-barrier (r7): R row staged ONCE as fp16 in LDS; L in 32 packed-h2
// registers. r9 post-mortem: d-outer loop + 64 VGPRs serialized the 12
// accumulator chains (VALU 18%, nothing busy). This version:
//  - k-OUTER / d-INNER: per channel-chunk k, 12 independent LDS reads + 48
//    VALU across 12 chains (dependent updates ~144 instrs apart).
//  - ZERO-ROW trick: t<d reads LDS row 256 (zeroed); adot(lh,0)=|lh| equals
//    the zero-pad contribution -> no divergence, no separate sl pass.
// RSTRIDE=36 dwords (32 data + 4 pad): banks 4(t+k) mod 32 -> 2-way (free).
// ---------------------------------------------------------------------------
#define RSTRIDE 36
#define ZROW WWX

__global__ __launch_bounds__(256) void cost_volume_k(const float* __restrict__ L,
                                                     const float* __restrict__ R,
                                                     float* __restrict__ cost) {
  __shared__ unsigned lsR[(WWX + 1) * RSTRIDE];   // 36 KB + 144 B (row 256 = 0)
  const int t = threadIdx.x;
  const int h = blockIdx.x;
  const int b = blockIdx.y;
  const size_t rowbase = ((size_t)(b * HHY + h)) * WWX;
  const float* Lrow = L + rowbase * CC;
  const float* Rrow = R + rowbase * CC;

  if (t < RSTRIDE) lsR[ZROW * RSTRIDE + t] = 0u;

  // Stage R: coalesced float4 loads (16 lanes/row), convert to fp16 pairs.
#pragma unroll
  for (int j = 0; j < 16; ++j) {
    const int fi = t + 256 * j;        // float4 id in [0,4096)
    const int w = fi >> 4;
    const int f4 = fi & 15;
    const float4 v = *(const float4*)(Rrow + (size_t)w * CC + 4 * f4);
    *(uint2*)(&lsR[w * RSTRIDE + f4 * 2]) =
        make_uint2(pkrtz(v.x, v.y), pkrtz(v.z, v.w));
  }

  // L: thread t owns row t; 16 float4 = 4 full 64B lines, converted to h2.
  unsigned lh[32];
#pragma unroll
  for (int k = 0; k < 16; ++k) {
    const float4 v = *(const float4*)(Lrow + (size_t)t * CC + 4 * k);
    lh[2 * k]     = pkrtz(v.x, v.y);
    lh[2 * k + 1] = pkrtz(v.z, v.w);
  }

  __syncthreads();   // the ONLY barrier

  // Per-d LDS row base; OOB d -> zero row (gives sum|L| = zero-pad value).
  int rb[DDp];
#pragma unroll
  for (int d = 0; d < DDp; ++d) rb[d] = (t >= d ? (t - d) : ZROW) * RSTRIDE;

  float acc[DDp];
#pragma unroll
  for (int d = 0; d < DDp; ++d) acc[d] = 0.f;

#pragma unroll
  for (int k = 0; k < 8; ++k) {
    const unsigned l0 = lh[4 * k], l1 = lh[4 * k + 1],
                   l2 = lh[4 * k + 2], l3 = lh[4 * k + 3];
#pragma unroll
    for (int d = 0; d < DDp; ++d) {
      const uint4 r = *(const uint4*)(&lsR[rb[d] + 4 * k]);
      float a = acc[d];
      a = adot(l0, r.x, a);
      a = adot(l1, r.y, a);
      a = adot(l2, r.z, a);
      a = adot(l3, r.w, a);
      acc[d] = a;
    }
  }

  float* cp = cost + (rowbase + t) * DDp;
#pragma unroll
  for (int d = 0; d < DDp; d += 4)
    *(float4*)(cp + d) = make_float4(acc[d], acc[d + 1], acc[d + 2], acc[d + 3]);
}

// ---------------------------------------------------------------------------
// conv0: 3x3x3, CIN=1 (f32 cost) -> COUT=4 (fp16 out). Block = one (b,h) row
// (XCD h-remap), thread = w. Row staged f32 in LDS stride 20; weights (108 f)
// wave-uniform global loads; fp16 pack on store (halves write traffic).
// ---------------------------------------------------------------------------
__global__ __launch_bounds__(256) void conv0_k(const float* __restrict__ x,
                                               const float* __restrict__ wt,
                                               const float* __restrict__ bs,
                                               hf* __restrict__ y) {
  constexpr int S = 20;
  __shared__ float ls[WWX * S];   // 20 KB
  const int t = threadIdx.x;
  const int id = blockIdx.x;
  const int h = ((id & 7) << 4) | ((id >> 3) & 15);  // XCD-contiguous h chunks
  const int b = id >> 7;

  float acc[DDp][4];
#pragma unroll
  for (int co = 0; co < 4; ++co) {
    const float bv = bs[co];
#pragma unroll
    for (int d = 0; d < DDp; ++d) acc[d][co] = bv;
  }

#pragma unroll
  for (int kh = 0; kh < 3; ++kh) {
    const int hh = h + kh - 1;
    if (hh < 0 || hh >= HHY) continue;  // block-uniform

    __syncthreads();
    const float* xr = x + ((size_t)(b * HHY + hh) * WWX) * DDp;
#pragma unroll
    for (int j = 0; j < 3; ++j) {
      const int fi4 = t + 256 * j;     // [0,768)
      const int w_ = fi4 / 3;
      const int k_ = fi4 - w_ * 3;
      *(float4*)(&ls[w_ * S + k_ * 4]) = ((const float4*)xr)[fi4];
    }
    __syncthreads();

#pragma unroll
    for (int kw = 0; kw < 3; ++kw) {
      const int ww = t + kw - 1;
      if (ww < 0 || ww >= WWX) continue;
      const float* lp = &ls[ww * S];

      const float* wp = wt + (size_t)(kh * 3 + kw) * 12;
      float wr[12];
#pragma unroll
      for (int i = 0; i < 12; ++i) wr[i] = wp[i];

      float v[DDp];
#pragma unroll
      for (int k = 0; k < 3; ++k)
        ((float4*)v)[k] = *(const float4*)(lp + 4 * k);
#pragma unroll
      for (int vo = 0; vo < DDp; ++vo)
#pragma unroll
        for (int kd = 0; kd < 3; ++kd) {
          const int d = vo + 1 - kd;
          if (d < 0 || d >= DDp) continue;
#pragma unroll
          for (int co = 0; co < 4; ++co)
            acc[d][co] += v[vo] * wr[kd * 4 + co];
        }
    }
  }

  unsigned ov[DDp * 2];
#pragma unroll
  for (int d = 0; d < DDp; ++d) {
    ov[d * 2]     = pkrtz(fmaxf(acc[d][0], 0.f), fmaxf(acc[d][1], 0.f));
    ov[d * 2 + 1] = pkrtz(fmaxf(acc[d][2], 0.f), fmaxf(acc[d][3], 0.f));
  }
  uint4* yp = (uint4*)(y + ((size_t)(b * HHY + h) * WWX + t) * (DDp * 4));
#pragma unroll
  for (int i = 0; i < 6; ++i) yp[i] = ((uint4*)ov)[i];
}

// ---------------------------------------------------------------------------
// Mid/final conv3d 3x3x3, CIN=4, fp16 activations [B,H,W,D,4], f32 accumulate
// via v_dot2_f32_f16 (2 MAC/instr). Block = one (b,h) row (XCD h-remap),
// thread = w. Rows staged fp16 in LDS (52-half stride = 26 uints; 26.6 KB ->
// 6 blocks/CU). Weights: fp16 repacked [tap][co][ci] -> wave-uniform uint
// scalar loads feed fdot2 directly. FUSE_SM: COUT=1 + softmax + regression.
// ---------------------------------------------------------------------------
template <int COUT, bool FUSE_SM>
__global__ __launch_bounds__(256) void convh_k(const hf* __restrict__ x,
                                               const hf* __restrict__ wh,
                                               const float* __restrict__ bs,
                                               void* __restrict__ yv) {
  constexpr int DCH = DDp * 4;        // 48 halves per w
  constexpr int SU  = 26;             // LDS stride per w in uints (52 halves)
  __shared__ unsigned lsu[WWX * SU];  // 26624 B

  const int t = threadIdx.x;
  const int id = blockIdx.x;
  const int h = ((id & 7) << 4) | ((id >> 3) & 15);
  const int b = id >> 7;

  float acc[DDp][COUT];
#pragma unroll
  for (int co = 0; co < COUT; ++co) {
    const float bv = bs[co];
#pragma unroll
    for (int d = 0; d < DDp; ++d) acc[d][co] = bv;
  }

  const unsigned* whu = (const unsigned*)wh;

#pragma unroll
  for (int kh = 0; kh < 3; ++kh) {
    const int hh = h + kh - 1;
    if (hh < 0 || hh >= HHY) continue;  // block-uniform

    __syncthreads();
    const uint4* xr = (const uint4*)(x + (size_t)(b * HHY + hh) * WWX * DCH);
#pragma unroll
    for (int j = 0; j < 6; ++j) {
      const int fi4 = t + 256 * j;     // [0,1536)
      const int w_ = fi4 / 6;
      const int k_ = fi4 - w_ * 6;
      const uint4 v = xr[fi4];
      unsigned* dst = &lsu[w_ * SU + k_ * 4];
      *(uint2*)(dst)     = make_uint2(v.x, v.y);
      *(uint2*)(dst + 2) = make_uint2(v.z, v.w);
    }
    __syncthreads();

#pragma unroll
    for (int kw = 0; kw < 3; ++kw) {
      const int ww = t + kw - 1;
      if (ww < 0 || ww >= WWX) continue;  // divergent only at row edges

      // per-tap fp16 weights, wave-uniform scalar loads
      unsigned w01[3][COUT], w23[3][COUT];
      const int tap3 = (kh * 3 + kw) * 3;
#pragma unroll
      for (int kd = 0; kd < 3; ++kd)
#pragma unroll
        for (int co = 0; co < COUT; ++co) {
          const int u0 = ((tap3 + kd) * COUT + co) * 2;
          w01[kd][co] = whu[u0];
          w23[kd][co] = whu[u0 + 1];
        }

      const unsigned* lp = &lsu[ww * SU];
#pragma unroll
      for (int vo = 0; vo < DDp; ++vo) {
        const uint2 xu = *(const uint2*)(lp + vo * 2);
        const h2 x01 = u2h(xu.x), x23 = u2h(xu.y);
#pragma unroll
        for (int kd = 0; kd < 3; ++kd) {
          const int d = vo + 1 - kd;
          if (d < 0 || d >= DDp) continue;
#pragma unroll
          for (int co = 0; co < COUT; ++co)
            acc[d][co] = FDOT2(x01, u2h(w01[kd][co]),
                         FDOT2(x23, u2h(w23[kd][co]), acc[d][co]));
        }
      }
    }
  }

  if constexpr (FUSE_SM) {
    float* y = (float*)yv;
    float mn = acc[0][0];
#pragma unroll
    for (int d = 1; d < DDp; ++d) mn = fminf(mn, acc[d][0]);
    float s = 0.f, sw = 0.f;
#pragma unroll
    for (int d = 0; d < DDp; ++d) {
      const float e = __expf(mn - acc[d][0]);
      s += e;
      sw += e * (float)d;
    }
    y[(size_t)(b * HHY + h) * WWX + t] = sw / s;
  } else {
    hf* y = (hf*)yv;
    unsigned ov[DDp * 2];
#pragma unroll
    for (int d = 0; d < DDp; ++d) {
      ov[d * 2]     = pkrtz(fmaxf(acc[d][0], 0.f), fmaxf(acc[d][1 % COUT], 0.f));
      ov[d * 2 + 1] = pkrtz(fmaxf(acc[d][2 % COUT], 0.f), fmaxf(acc[d][3 % COUT], 0.f));
    }
    uint4* yp = (uint4*)(y + ((size_t)(b * HHY + h) * WWX + t) * DCH);
#pragma unroll
    for (int i = 0; i < 6; ++i) yp[i] = ((uint4*)ov)[i];
  }
}

// ---------------------------------------------------------------------------
// 8x bilinear upsample, 4 outputs per thread (2 input cols x 2 rows -> 4 loads,
// 1 float4 store). jax half-pixel convention; edge renorm == index clamp.
// ---------------------------------------------------------------------------
__global__ __launch_bounds__(256) void resize4_k(const float* __restrict__ pred,
                                                 float* __restrict__ out) {
  const int idx = blockIdx.x * 256 + threadIdx.x;
  const int xg = idx & 511;
  const int y = (idx >> 9) & 1023;
  const int b = idx >> 19;

  const int parity = xg & 1;
  const int m = xg >> 1;
  const int x0 = m - 1 + parity;
  const int x0c = max(x0, 0);
  const int x1c = min(x0 + 1, WWX - 1);
  const float wx0 = (parity ? 0.0625f : 0.5625f);

  const int py = y & 7;
  const int my = y >> 3;
  const int y0 = my - 1 + (py >= 4 ? 1 : 0);
  const float wy = (py >= 4) ? 0.0625f + (py - 4) * 0.125f : 0.5625f + py * 0.125f;
  const int y0c = max(y0, 0);
  const int y1c = min(y0 + 1, HHY - 1);

  const float* pb = pred + (size_t)b * HHY * WWX;
  const float a = pb[y0c * WWX + x0c];
  const float bv = pb[y0c * WWX + x1c];
  const float c = pb[y1c * WWX + x0c];
  const float d = pb[y1c * WWX + x1c];

  const float top0 = a + (bv - a) * wx0;
  const float bot0 = c + (d - c) * wx0;
  const float dtop = (bv - a) * 0.125f;
  const float dbot = (d - c) * 0.125f;

  float4 o;
  o.x = top0 + wy * (bot0 - top0);
  o.y = (top0 + dtop) + wy * ((bot0 + dbot) - (top0 + dtop));
  o.z = (top0 + 2.f * dtop) + wy * ((bot0 + 2.f * dbot) - (top0 + 2.f * dtop));
  o.w = (top0 + 3.f * dtop) + wy * ((bot0 + 3.f * dbot) - (top0 + 3.f * dtop));

  *(float4*)(out + (size_t)idx * 4) = o;
}

// ---------------------------------------------------------------------------
extern "C" void kernel_launch(void* const* d_in, const int* in_sizes, int n_in,
                              void* d_out, int out_size, void* d_ws, size_t ws_size,
                              hipStream_t stream) {
  const float* feat_l = (const float*)d_in[0];
  const float* feat_r = (const float*)d_in[1];
  const float* w0 = (const float*)d_in[2];
  const float* b0 = (const float*)d_in[3];
  const float* w1 = (const float*)d_in[4];
  const float* b1 = (const float*)d_in[5];
  const float* w2 = (const float*)d_in[6];
  const float* b2 = (const float*)d_in[7];
  const float* w3 = (const float*)d_in[8];
  const float* b3 = (const float*)d_in[9];
  const float* wf = (const float*)d_in[10];
  const float* bf = (const float*)d_in[11];
  float* out = (float*)d_out;

  // ws layout: A,B = fp16 activation ping-pong [B,H,W,D,4] (50.3 MB each);
  // C = f32 cost volume (25.2 MB); P = f32 pred (2.1 MB); Wh = fp16 weights.
  char* ws = (char*)d_ws;
  hf*    A  = (hf*)ws;
  hf*    Bf = (hf*)(ws + 50331648);
  float* C  = (float*)(ws + 100663296);
  float* P  = (float*)(ws + 125829120);
  hf*    Wh = (hf*)(ws + 127926272);

  dim3 blk(256);
  prep_k<<<dim3(1), blk, 0, stream>>>(w1, w2, w3, wf, Wh);
  cost_volume_k<<<dim3(HHY, BB), blk, 0, stream>>>(feat_l, feat_r, C);
  conv0_k<<<dim3(HHY * BB), blk, 0, stream>>>(C, w0, b0, A);
  convh_k<4, false><<<dim3(HHY * BB), blk, 0, stream>>>(A,  Wh,        b1, Bf);
  convh_k<4, false><<<dim3(HHY * BB), blk, 0, stream>>>(Bf, Wh + 432,  b2, A);
  convh_k<4, false><<<dim3(HHY * BB), blk, 0, stream>>>(A,  Wh + 864,  b3, Bf);
  convh_k<1, true ><<<dim3(HHY * BB), blk, 0, stream>>>(Bf, Wh + 1296, bf, P);

  const int ngroups = BB * HOUT * (WOUT / 4);
  resize4_k<<<dim3(ngroups / 256), blk, 0, stream>>>(P, out);
}